// Round 5
// baseline (77.746 us; speedup 1.0000x reference)
//
#include <hip/hip_runtime.h>

// probs = |U^{x8} f|^2 / ||f||^2, U = 8x8 complex gate on each of 8 qubit triples.
// MFMA: per 3-qubit axis, D = A*B, A(16x16 f16) = [[Gr,-Gi],[Gi,Gr]], B = 16
// rest-columns of [Xr;Xi], f32 accumulate (v_mfma_f32_16x16x16_f16).
//
// k_pass1 (axes A3..A7, low 15 bits; 512 blocks x 1024 thr, 128KB LDS):
//   - stage A3 fused with global load: B-fragments read straight from f
//     (lanes kg<2 load 4 floats @16KB stride, 64B-coalesced; Xi half = 0),
//     ||f||^2 partials fused in; writes L1 via the round-4 stage-write formula.
//   - 3 uniform in-LDS stages (A4,A5,A6), rotation k<-e3,e3<-e2,e2<-e1,e1<-e0,
//     e0<-new digit, on halfword layout [e3|e2|e1|e0|p|k], swizzle SW1.
//   - stage A7 fused with writeout: intermediate = identity-layout (re,im)
//     f16 dword per element, written as uint4 chunks.
// k_pass2 (axes A0..A2; 2048 blocks x 256 thr, 32KB LDS = 512 hi x 16 lo):
//   - tile layout [s1|s0|sp(4)|p|k] halfwords, swizzle SW2 (bits[6:4] ^=
//     bits[9:7]) -> all accesses <=2-way banks, b64/b128 alignment kept.
//   - fill: 4-hi-grouped uint4 reads -> packed b64 plane writes.
//   - 2 uniform LDS stages (A2,A1): b64 frag reads, packed b128 writes.
//   - stage A0 fused with probs writeout (re^2+im^2 across plane halves via
//     shfl_xor 32), block reads/writes the same private region of d_out.

typedef _Float16 f16;
typedef _Float16 f16x4 __attribute__((ext_vector_type(4)));
typedef float f32x4 __attribute__((ext_vector_type(4)));
typedef unsigned int u32;
typedef unsigned short u16;

__device__ __forceinline__ u32 SW1(u32 a) { return a ^ (((a >> 8) & 0xFu) << 3); }
__device__ __forceinline__ u32 SW2(u32 a) { return a ^ (((a >> 7) & 0x7u) << 4); }

__device__ __forceinline__ u32 PK(float x, float y) {
  return __builtin_bit_cast(u32, __builtin_amdgcn_cvt_pkrtz(x, y));
}

// A fragment for v_mfma_f32_16x16x16_f16: lane holds A[row=l&15][k=(l>>4)*4+e].
// A = [[Gr, -Gi], [Gi, Gr]]; rows 0-7 -> re out, 8-15 -> im out; k<8 hits Xr.
__device__ __forceinline__ f16x4 build_A(const float* __restrict__ gr,
                                         const float* __restrict__ gi, int l) {
  const int row = l & 15, kg = l >> 4;
  const int pg = row & 7, rpl = row >> 3, kpl = kg >> 1;
  f16x4 a;
#pragma unroll
  for (int e = 0; e < 4; ++e) {
    const int j = (kg & 1) * 4 + e;
    const float grv = gr[pg * 8 + j], giv = gi[pg * 8 + j];
    const float v = rpl == 0 ? (kpl == 0 ? grv : -giv) : (kpl == 0 ? giv : grv);
    a[e] = (f16)v;
  }
  return a;
}

// ---------------- pass1: uniform in-LDS stage (16 waves) ----------------
__device__ __forceinline__ void p1_stage(char* lb, f16x4 A, int w, int l) {
  const int kg = l >> 4, c = l & 15, c3 = c >> 3, p = kg >> 1;
  const u32 rb = (u32)(w * 512 + c * 32 + kg * 8);
  const f32x4 Z = {0.f, 0.f, 0.f, 0.f};
  f32x4 acc[16];
#pragma unroll
  for (int g = 0; g < 4; ++g) {
#pragma unroll
    for (int m = 0; m < 4; ++m) {
      const int j = (g & 1) + m * 2 + (g >> 1) * 8;
      const uint2 bw = *(const uint2*)(lb + SW1(rb + (u32)j * 8192u));
      acc[g * 4 + m] = __builtin_amdgcn_mfma_f32_16x16x16f16(
          A, __builtin_bit_cast(f16x4, bw), Z, 0, 0, 0);
    }
  }
  __syncthreads();  // all reads everywhere done -> in-place writes safe
  const u32 wl = (u32)(((w >> 2) << 14) + (((w & 3) * 2 + c3) << 11) +
                       ((c & 7) << 8) + ((kg & 1) << 7) + (p << 4));
#pragma unroll
  for (int g = 0; g < 4; ++g) {
#pragma unroll
    for (int rr = 0; rr < 4; ++rr) {
      const u32 d0 = PK(acc[g * 4 + 0][rr], acc[g * 4 + 1][rr]);
      const u32 d1 = PK(acc[g * 4 + 2][rr], acc[g * 4 + 3][rr]);
      const u32 lg = wl + (u32)(((g & 1) << 16) + ((g >> 1) << 3) + (rr << 5));
      *(uint2*)(lb + SW1(lg)) = make_uint2(d0, d1);
    }
  }
  __syncthreads();
}

__global__ __launch_bounds__(1024, 4) void k_pass1(
    const float* __restrict__ f, const float* __restrict__ gr,
    const float* __restrict__ gi, uint4* __restrict__ st,
    float* __restrict__ wsp) {
  __shared__ __align__(16) char lb[131072];
  __shared__ float red[16];
  const int t = threadIdx.x, l = t & 63, w = t >> 6, blk = blockIdx.x;
  const int kg = l >> 4, c = l & 15, c3 = c >> 3, p = kg >> 1;
  const f16x4 A = build_A(gr, gi, l);
  const f32x4 Z = {0.f, 0.f, 0.f, 0.f};

  // ---- fused stage A3: B-fragments straight from global, + ||f||^2 ----
  // col(12b) = A4*512+A5*64+A6*8+A7 with A4=j>>1, A5=(j&1)*4+(w>>2),
  // A6=(w&3)*2+(c>>3), A7=c&7; rows: p=kg>>1, A3=kg*4+e (kg<2 real, else 0).
  float s = 0.f;
  {
    const float* fb = f + ((size_t)blk << 15) + (size_t)(kg & 1) * 16384;
    f32x4 acc[16];
#pragma unroll
    for (int g = 0; g < 4; ++g) {
#pragma unroll
      for (int m = 0; m < 4; ++m) {
        const int j = (g & 1) + m * 2 + (g >> 1) * 8;
        const int col = (j >> 1) * 512 + (j & 1) * 256 + (w >> 2) * 64 +
                        (w & 3) * 16 + c;
        f16x4 b = {(f16)0.f, (f16)0.f, (f16)0.f, (f16)0.f};
        if (kg < 2) {
          const float v0 = fb[col];
          const float v1 = fb[col + 4096];
          const float v2 = fb[col + 8192];
          const float v3 = fb[col + 12288];
          s += v0 * v0 + v1 * v1 + v2 * v2 + v3 * v3;
          b[0] = (f16)v0; b[1] = (f16)v1; b[2] = (f16)v2; b[3] = (f16)v3;
        }
        acc[g * 4 + m] = __builtin_amdgcn_mfma_f32_16x16x16f16(A, b, Z, 0, 0, 0);
      }
    }
    // write L1 (standard stage-write formula; LDS is empty -> no pre-barrier)
    const u32 wl = (u32)(((w >> 2) << 14) + (((w & 3) * 2 + c3) << 11) +
                         ((c & 7) << 8) + ((kg & 1) << 7) + (p << 4));
#pragma unroll
    for (int g = 0; g < 4; ++g) {
#pragma unroll
      for (int rr = 0; rr < 4; ++rr) {
        const u32 d0 = PK(acc[g * 4 + 0][rr], acc[g * 4 + 1][rr]);
        const u32 d1 = PK(acc[g * 4 + 2][rr], acc[g * 4 + 3][rr]);
        const u32 lg = wl + (u32)(((g & 1) << 16) + ((g >> 1) << 3) + (rr << 5));
        *(uint2*)(lb + SW1(lg)) = make_uint2(d0, d1);
      }
    }
  }
  // norm partial: reduce within wave, stash, single barrier covers LDS writes
#pragma unroll
  for (int off = 32; off; off >>= 1) s += __shfl_down(s, off, 64);
  if (l == 0) red[w] = s;
  __syncthreads();
  if (t == 0) {
    float a = 0.f;
#pragma unroll
    for (int i = 0; i < 16; ++i) a += red[i];
    wsp[blk] = a;
  }

  p1_stage(lb, A, w, l);  // A4
  p1_stage(lb, A, w, l);  // A5
  p1_stage(lb, A, w, l);  // A6

  // ---- stage A7 fused with writeout (identity-layout intermediate) ----
  // L4 = [A3|A4|A5|A6|p|A7]: A3=j>>1, A4=(j&1)*4+(w>>2), A5=(w&3)*2+c3, A6=c&7
  const u32 rb = (u32)(w * 512 + c * 32 + kg * 8);
  const size_t ob = (size_t)blk * 8192;  // uint4 units
#pragma unroll
  for (int j = 0; j < 16; ++j) {
    const uint2 bw = *(const uint2*)(lb + SW1(rb + (u32)j * 8192u));
    const f32x4 a = __builtin_amdgcn_mfma_f32_16x16x16f16(
        A, __builtin_bit_cast(f16x4, bw), Z, 0, 0, 0);
    const u32 h01 = PK(a[0], a[1]), h23 = PK(a[2], a[3]);
    const u32 q01 = __shfl_xor(h01, 32, 64), q23 = __shfl_xor(h23, 32, 64);
    if (p == 0) {  // partner (p=1) holds im parts
      const int A3 = j >> 1, A4 = (j & 1) * 4 + (w >> 2), A5 = (w & 3) * 2 + c3;
      uint4 vv;
      vv.x = (h01 & 0xffffu) | (q01 << 16);
      vv.y = (h01 >> 16) | (q01 & 0xffff0000u);
      vv.z = (h23 & 0xffffu) | (q23 << 16);
      vv.w = (h23 >> 16) | (q23 & 0xffff0000u);
      st[ob + (u32)(((A3 * 64 + A4 * 8 + A5) << 4) + ((c & 7) << 1) + (kg & 1))] = vv;
    }
  }
}

// ---------------- pass2: 32KB tile, 4 waves ----------------
// halfword layout h = s1*2048 + s0*256 + sp*16 + p*8 + k  (byte = 2h, SW2).
// L0: k=A2,s0=A0,s1=A1 -> stage A2 -> L1: k=A1,s0=A2,s1=A0 -> stage A1 ->
// L2: k=A0,s0=A1,s1=A2 -> final stage A0 + probs.
__device__ __forceinline__ void p2_stage(char* lb, f16x4 A, int w, int l) {
  const int kg = l >> 4, c = l & 15, pp = kg >> 1;
  const f32x4 Z = {0.f, 0.f, 0.f, 0.f};
  f32x4 acc[16];
#pragma unroll
  for (int g = 0; g < 4; ++g) {
#pragma unroll
    for (int m = 0; m < 4; ++m) {
      const int j = (g & 1) + m * 2 + (g >> 1) * 8;
      const u32 rb = (u32)(j * 2048 + w * 512 + c * 32 + kg * 8);
      const uint2 bw = *(const uint2*)(lb + SW2(rb));
      acc[g * 4 + m] = __builtin_amdgcn_mfma_f32_16x16x16f16(
          A, __builtin_bit_cast(f16x4, bw), Z, 0, 0, 0);
    }
  }
  __syncthreads();
  // packed b128 writes: for (pe,rr), halfword slots k'=j>>1 are consecutive
#pragma unroll
  for (int pe = 0; pe < 2; ++pe) {
#pragma unroll
    for (int rr = 0; rr < 4; ++rr) {
      uint4 vv;
      vv.x = PK(acc[pe * 4 + 0][rr], acc[pe * 4 + 1][rr]);
      vv.y = PK(acc[pe * 4 + 2][rr], acc[pe * 4 + 3][rr]);
      vv.z = PK(acc[(2 + pe) * 4 + 0][rr], acc[(2 + pe) * 4 + 1][rr]);
      vv.w = PK(acc[(2 + pe) * 4 + 2][rr], acc[(2 + pe) * 4 + 3][rr]);
      const u32 wb = (u32)((pe * 4 + w) * 4096 + ((kg & 1) * 4 + rr) * 512 +
                           c * 32 + pp * 16);
      *(uint4*)(lb + SW2(wb)) = vv;
    }
  }
  __syncthreads();
}

__global__ __launch_bounds__(256, 4) void k_pass2(
    const uint4* gp, const float* __restrict__ gr, const float* __restrict__ gi,
    const float* __restrict__ wsp, float* out) {
  __shared__ __align__(16) char lb[32768];
  __shared__ float red[4];
  const int t = threadIdx.x, l = t & 63, w = t >> 6;
  const int kg = l >> 4, c = l & 15, pp = kg >> 1;
  const int b9 = blockIdx.x >> 2, q = blockIdx.x & 3;
  const f16x4 A = build_A(gr, gi, l);
  const f32x4 Z = {0.f, 0.f, 0.f, 0.f};

  // norm: reduce pass1 partials (deterministic)
  float sp_ = wsp[t] + wsp[t + 256];
#pragma unroll
  for (int off = 32; off; off >>= 1) sp_ += __shfl_down(sp_, off, 64);
  if (l == 0) red[w] = sp_;

  // ---- fill: 4-hi-grouped uint4 reads -> packed b64 plane writes ----
  // element n = hi*2^15 + b9*64 + q*16 + sp; uint4 idx = hi*8192 + b9*16 + q*4 + u
  {
    const int z = t >> 2, u = t & 3;
    const int A1 = z & 7, A0 = z >> 3;
#pragma unroll
    for (int a2g = 0; a2g < 2; ++a2g) {
      uint4 raw[4];
#pragma unroll
      for (int d = 0; d < 4; ++d)
        raw[d] = gp[(size_t)(z * 8 + 4 * a2g + d) * 8192 + (u32)(b9 * 16 + q * 4 + u)];
#pragma unroll
      for (int v = 0; v < 4; ++v) {
        const u32 w0 = v == 0 ? raw[0].x : v == 1 ? raw[0].y : v == 2 ? raw[0].z : raw[0].w;
        const u32 w1 = v == 0 ? raw[1].x : v == 1 ? raw[1].y : v == 2 ? raw[1].z : raw[1].w;
        const u32 w2 = v == 0 ? raw[2].x : v == 1 ? raw[2].y : v == 2 ? raw[2].z : raw[2].w;
        const u32 w3 = v == 0 ? raw[3].x : v == 1 ? raw[3].y : v == 2 ? raw[3].z : raw[3].w;
        const int sp = u * 4 + v;
        const u32 base = (u32)(A1 * 4096 + A0 * 512 + sp * 32 + 8 * a2g);
        // re plane (p=0): lo halves, k = A2 = 4*a2g + d consecutive
        *(uint2*)(lb + SW2(base)) =
            make_uint2((w0 & 0xffffu) | (w1 << 16), (w2 & 0xffffu) | (w3 << 16));
        // im plane (p=1)
        *(uint2*)(lb + SW2(base + 16u)) =
            make_uint2((w0 >> 16) | (w1 & 0xffff0000u), (w2 >> 16) | (w3 & 0xffff0000u));
      }
    }
  }
  __syncthreads();
  const float inv = 1.0f / (red[0] + red[1] + red[2] + red[3]);

  p2_stage(lb, A, w, l);  // A2
  p2_stage(lb, A, w, l);  // A1

  // ---- final stage A0 + probs writeout ----
  // L2: A2 = j>>1, A1 = (j&1)*4+w, sp = c; rows: p=kg>>1, A0 = (kg&1)*4+rr
#pragma unroll
  for (int j = 0; j < 16; ++j) {
    const u32 rb = (u32)(j * 2048 + w * 512 + c * 32 + kg * 8);
    const uint2 bw = *(const uint2*)(lb + SW2(rb));
    const f32x4 a = __builtin_amdgcn_mfma_f32_16x16x16f16(
        A, __builtin_bit_cast(f16x4, bw), Z, 0, 0, 0);
    const int A2 = j >> 1, A1 = (j & 1) * 4 + w;
    const size_t gb = ((size_t)A1 << 18) + ((size_t)A2 << 15) +
                      (u32)(b9 * 64 + q * 16 + c);
#pragma unroll
    for (int rr = 0; rr < 4; ++rr) {
      float qv = a[rr] * a[rr];
      qv += __shfl_xor(qv, 32, 64);  // re^2 + im^2 from partner plane
      if ((rr >> 1) == pp) {         // p=0 stores rr 0,1; p=1 stores rr 2,3
        const size_t A0 = (size_t)((kg & 1) * 4 + rr);
        out[gb + (A0 << 21)] = qv * inv;
      }
    }
  }
}

extern "C" void kernel_launch(void* const* d_in, const int* in_sizes, int n_in,
                              void* d_out, int out_size, void* d_ws,
                              size_t ws_size, hipStream_t stream) {
  (void)in_sizes; (void)n_in; (void)out_size; (void)ws_size;
  const float* f = (const float*)d_in[0];
  const float* gr = (const float*)d_in[1];
  const float* gi = (const float*)d_in[2];
  float* wsp = (float*)d_ws;  // 512 floats

  k_pass1<<<dim3(512), dim3(1024), 0, stream>>>(f, gr, gi, (uint4*)d_out, wsp);
  k_pass2<<<dim3(2048), dim3(256), 0, stream>>>((const uint4*)d_out, gr, gi,
                                                wsp, (float*)d_out);
}